// Round 1
// baseline (708.864 us; speedup 1.0000x reference)
//
#include <hip/hip_runtime.h>
#include <hip/hip_bf16.h>
#include <cstdint>

#define B_  64
#define T_  1024
#define I_  256
#define H1_ 512
#define H2_ 512
#define O_  128

typedef unsigned long long u64;

// ---------------------------------------------------------------------------
// Prep: transpose W2 [H2][H1] -> W2T [H1][H2], Wo [O][H2] -> WoT [H2][O]
// ---------------------------------------------------------------------------
__global__ __launch_bounds__(256) void prep_transpose(
    const float* __restrict__ W2, const float* __restrict__ Wo,
    float* __restrict__ W2T, float* __restrict__ WoT)
{
    int idx = blockIdx.x * 256 + threadIdx.x;
    if (idx < H1_ * H2_) {
        int h1 = idx / H2_, h2 = idx % H2_;
        W2T[idx] = W2[h2 * H1_ + h1];
    }
    if (idx < H2_ * O_) {
        int h2 = idx / O_, o = idx % O_;
        WoT[idx] = Wo[o * H2_ + h2];
    }
}

// ---------------------------------------------------------------------------
// K1: f32 GEMM  din1[m][n] = dot(X[m,:], W1[n,:]) + b1[n]
//     M = cur_b*1024, N = 512, K = 256.  Tile 128x64x32, 256 threads.
// ---------------------------------------------------------------------------
#define BM 128
#define BN 64
#define BK 32

__global__ __launch_bounds__(256) void gemm1_kernel(
    const float* __restrict__ X,   // [M][256]
    const float* __restrict__ W1,  // [512][256]
    const float* __restrict__ b1,  // [512]
    float* __restrict__ out,       // [M][512]
    int M)
{
    __shared__ float As[BK][BM + 4];  // [k][m], pad 4 -> 16B-aligned rows
    __shared__ float Bs[BK][BN + 4];  // [k][n]

    int tid = threadIdx.x;
    int m0 = blockIdx.x * BM;
    int n0 = blockIdx.y * BN;
    int tx = tid & 15;        // col group (4 cols each)
    int ty = tid >> 4;        // row group (8 rows each)

    float acc[8][4] = {};

    for (int k0 = 0; k0 < I_; k0 += BK) {
        // load A tile: 128x32 floats = 1024 float4, 4 per thread
        #pragma unroll
        for (int i = 0; i < 4; i++) {
            int idx = tid + i * 256;
            int row = idx >> 3;
            int kq  = idx & 7;
            float4 v = *reinterpret_cast<const float4*>(
                X + (size_t)(m0 + row) * I_ + k0 + kq * 4);
            As[kq * 4 + 0][row] = v.x;
            As[kq * 4 + 1][row] = v.y;
            As[kq * 4 + 2][row] = v.z;
            As[kq * 4 + 3][row] = v.w;
        }
        // load B tile: 64x32 floats = 512 float4, 2 per thread
        #pragma unroll
        for (int i = 0; i < 2; i++) {
            int idx = tid + i * 256;
            int row = idx >> 3;
            int kq  = idx & 7;
            float4 v = *reinterpret_cast<const float4*>(
                W1 + (size_t)(n0 + row) * I_ + k0 + kq * 4);
            Bs[kq * 4 + 0][row] = v.x;
            Bs[kq * 4 + 1][row] = v.y;
            Bs[kq * 4 + 2][row] = v.z;
            Bs[kq * 4 + 3][row] = v.w;
        }
        __syncthreads();

        #pragma unroll
        for (int kk = 0; kk < BK; kk++) {
            float4 a0 = *reinterpret_cast<const float4*>(&As[kk][ty * 8]);
            float4 a1 = *reinterpret_cast<const float4*>(&As[kk][ty * 8 + 4]);
            float4 bv = *reinterpret_cast<const float4*>(&Bs[kk][tx * 4]);
            float a[8] = {a0.x, a0.y, a0.z, a0.w, a1.x, a1.y, a1.z, a1.w};
            float b[4] = {bv.x, bv.y, bv.z, bv.w};
            #pragma unroll
            for (int i = 0; i < 8; i++)
                #pragma unroll
                for (int j = 0; j < 4; j++)
                    acc[i][j] = fmaf(a[i], b[j], acc[i][j]);
        }
        __syncthreads();
    }

    float4 bb = *reinterpret_cast<const float4*>(b1 + n0 + tx * 4);
    #pragma unroll
    for (int i = 0; i < 8; i++) {
        int m = m0 + ty * 8 + i;
        float4 v;
        v.x = acc[i][0] + bb.x;
        v.y = acc[i][1] + bb.y;
        v.z = acc[i][2] + bb.z;
        v.w = acc[i][3] + bb.w;
        *reinterpret_cast<float4*>(out + (size_t)m * H1_ + n0 + tx * 4) = v;
    }
}

// ---------------------------------------------------------------------------
// K2: layer-1 LIF scan. One thread per (b, h1). Records spikes into bitmasks.
// ---------------------------------------------------------------------------
__global__ __launch_bounds__(256) void scan1_kernel(
    const float* __restrict__ din1,       // [nb][1024][512]
    const float* __restrict__ tau_m1,
    const float* __restrict__ tau_n1,
    u64* __restrict__ s1_bits,            // [B][1024][8]
    u64* __restrict__ s1_any,             // [B][16]
    int b0)
{
    int idx = blockIdx.x * 256 + threadIdx.x;
    int bl  = idx >> 9;          // local chunk batch index
    int b   = b0 + bl;
    int h   = idx & 511;

    float beta    = 1.f / (1.f + expf(-tau_n1[h]));
    float alpha   = 1.f / (1.f + expf(-tau_m1[h]));
    float ombeta  = 1.f - beta;
    float omalpha = 1.f - alpha;

    float d1 = 0.f, mem = 0.f;
    const float* p = din1 + (size_t)bl * (T_ * H1_) + h;

    #pragma unroll 4
    for (int t = 0; t < T_; t++) {
        float din = p[(size_t)t * H1_];
        d1  = beta * d1 + ombeta * din;
        mem = alpha * mem + omalpha * d1;
        if (mem > 1.0f) {
            atomicOr(&s1_bits[((size_t)b * T_ + t) * 8 + (h >> 6)], 1ull << (h & 63));
            atomicOr(&s1_any[b * 16 + (t >> 6)], 1ull << (t & 63));
            mem = 0.f;
        }
    }
}

// ---------------------------------------------------------------------------
// K3: layer-2 LIF scan. d_in2 = b2 + sum over spiking h1 of W2T[h1][h2].
// ---------------------------------------------------------------------------
__global__ __launch_bounds__(256) void scan2_kernel(
    const float* __restrict__ W2T,        // [H1][H2]
    const float* __restrict__ b2,
    const float* __restrict__ tau_m2,
    const float* __restrict__ tau_n2,
    const u64* __restrict__ s1_bits,
    const u64* __restrict__ s1_any,
    u64* __restrict__ s2_bits,
    u64* __restrict__ s2_any,
    int b0)
{
    int idx = blockIdx.x * 256 + threadIdx.x;
    int b   = b0 + (idx >> 9);
    int h   = idx & 511;

    float beta    = 1.f / (1.f + expf(-tau_n2[h]));
    float alpha   = 1.f / (1.f + expf(-tau_m2[h]));
    float ombeta  = 1.f - beta;
    float omalpha = 1.f - alpha;
    float bias    = b2[h];

    float d2 = 0.f, mem = 0.f;

    for (int tw = 0; tw < 16; tw++) {
        u64 aw = s1_any[b * 16 + tw];   // wave-uniform (512 threads per b)
        for (int t2 = 0; t2 < 64; t2++) {
            int t = tw * 64 + t2;
            float din = bias;
            if ((aw >> t2) & 1ull) {
                const u64* w = s1_bits + ((size_t)b * T_ + t) * 8;
                for (int q = 0; q < 8; q++) {
                    u64 m = w[q];
                    while (m) {
                        int h1 = __ffsll(m) - 1;
                        din += W2T[(size_t)(q * 64 + h1) * H2_ + h];
                        m &= m - 1;
                    }
                }
            }
            d2  = beta * d2 + ombeta * din;
            mem = alpha * mem + omalpha * d2;
            if (mem > 1.0f) {
                atomicOr(&s2_bits[((size_t)b * T_ + t) * 8 + (h >> 6)], 1ull << (h & 63));
                atomicOr(&s2_any[b * 16 + (t >> 6)], 1ull << (t & 63));
                mem = 0.f;
            }
        }
    }
}

// ---------------------------------------------------------------------------
// K4: output  out[b][t][o] = sigmoid(bo[o] + sum over spiking h2 of WoT[h2][o])
// ---------------------------------------------------------------------------
__global__ __launch_bounds__(256) void out_kernel(
    const float* __restrict__ WoT,        // [H2][O]
    const float* __restrict__ bo,
    const u64* __restrict__ s2_bits,
    const u64* __restrict__ s2_any,
    float* __restrict__ out,
    int b0)
{
    int idx = blockIdx.x * 256 + threadIdx.x;
    int o = idx & 127;
    int t = (idx >> 7) & 1023;
    int b = b0 + (idx >> 17);

    float z = bo[o];
    if ((s2_any[b * 16 + (t >> 6)] >> (t & 63)) & 1ull) {
        const u64* w = s2_bits + ((size_t)b * T_ + t) * 8;
        for (int q = 0; q < 8; q++) {
            u64 m = w[q];
            while (m) {
                int h2 = __ffsll(m) - 1;
                z += WoT[(size_t)(q * 64 + h2) * O_ + o];
                m &= m - 1;
            }
        }
    }
    out[((size_t)b * T_ + t) * O_ + o] = 1.f / (1.f + expf(-z));
}

// ---------------------------------------------------------------------------
// Launch
// ---------------------------------------------------------------------------
extern "C" void kernel_launch(void* const* d_in, const int* in_sizes, int n_in,
                              void* d_out, int out_size, void* d_ws, size_t ws_size,
                              hipStream_t stream)
{
    const float* x      = (const float*)d_in[0];   // [B][T][I]
    const float* W1     = (const float*)d_in[1];   // [H1][I]
    const float* b1     = (const float*)d_in[2];
    const float* tau_m1 = (const float*)d_in[3];
    const float* tau_n1 = (const float*)d_in[4];
    const float* W2     = (const float*)d_in[5];   // [H2][H1]
    const float* b2     = (const float*)d_in[6];
    const float* tau_m2 = (const float*)d_in[7];
    const float* tau_n2 = (const float*)d_in[8];
    const float* Wo     = (const float*)d_in[9];   // [O][H2]
    const float* bo     = (const float*)d_in[10];
    float* out = (float*)d_out;

    // ws layout
    char* ws = (char*)d_ws;
    size_t off = 0;
    float* W2T = (float*)(ws + off); off += (size_t)H1_ * H2_ * 4;       // 1 MB
    float* WoT = (float*)(ws + off); off += (size_t)H2_ * O_ * 4;        // 256 KB
    size_t zero_begin = off;
    u64* s1_any  = (u64*)(ws + off); off += (size_t)B_ * 16 * 8;         // 8 KB
    u64* s2_any  = (u64*)(ws + off); off += (size_t)B_ * 16 * 8;         // 8 KB
    u64* s1_bits = (u64*)(ws + off); off += (size_t)B_ * T_ * 8 * 8;     // 4 MB
    u64* s2_bits = (u64*)(ws + off); off += (size_t)B_ * T_ * 8 * 8;     // 4 MB
    size_t zero_bytes = off - zero_begin;
    float* din1 = (float*)(ws + off);
    size_t avail = (ws_size > off) ? (ws_size - off) : 0;
    const size_t per_b = (size_t)T_ * H1_ * 4;                           // 2 MB
    int bchunk = (int)(avail / per_b);
    if (bchunk < 1) bchunk = 1;
    if (bchunk > B_) bchunk = B_;

    // zero the spike bitmasks / summaries
    hipMemsetAsync(ws + zero_begin, 0, zero_bytes, stream);

    // transpose weights
    prep_transpose<<<dim3((H1_ * H2_ + 255) / 256), dim3(256), 0, stream>>>(
        W2, Wo, W2T, WoT);

    for (int b0 = 0; b0 < B_; b0 += bchunk) {
        int cur = B_ - b0 < bchunk ? B_ - b0 : bchunk;
        int M = cur * T_;

        gemm1_kernel<<<dim3(M / BM, H1_ / BN), dim3(256), 0, stream>>>(
            x + (size_t)b0 * T_ * I_, W1, b1, din1, M);

        scan1_kernel<<<dim3(cur * 2), dim3(256), 0, stream>>>(
            din1, tau_m1, tau_n1, s1_bits, s1_any, b0);

        scan2_kernel<<<dim3(cur * 2), dim3(256), 0, stream>>>(
            W2T, b2, tau_m2, tau_n2, s1_bits, s1_any, s2_bits, s2_any, b0);

        out_kernel<<<dim3(cur * 512), dim3(256), 0, stream>>>(
            WoT, bo, s2_bits, s2_any, out, b0);
    }
}

// Round 4
// 252.215 us; speedup vs baseline: 2.8106x; 2.8106x over previous
//
#include <hip/hip_runtime.h>
#include <hip/hip_bf16.h>
#include <cstdint>

#define B_  64
#define T_  1024
#define I_  256
#define H1_ 512
#define H2_ 512
#define O_  128
#define CH_ 16
#define LL_ 64
#define GUARD_ 1e-3f

typedef unsigned long long u64;
typedef __attribute__((ext_vector_type(8))) short s8v;
typedef __attribute__((ext_vector_type(4))) float f4v;
typedef __attribute__((ext_vector_type(8))) unsigned short us8v;

__device__ __forceinline__ unsigned short f2bf(float f) {
    unsigned int u = __float_as_uint(f);
    unsigned int r = (u + 0x7FFFu + ((u >> 16) & 1u)) >> 16;
    return (unsigned short)r;
}

// ---------------------------------------------------------------------------
// Prep: W2 -> W2T, Wo -> WoT, W1 -> bf16
// ---------------------------------------------------------------------------
__global__ __launch_bounds__(256) void prep_kernel(
    const float* __restrict__ W2, const float* __restrict__ Wo,
    const float* __restrict__ W1,
    float* __restrict__ W2T, float* __restrict__ WoT,
    unsigned short* __restrict__ W1b)
{
    int idx = blockIdx.x * 256 + threadIdx.x;
    if (idx < H1_ * H2_) {
        int h1 = idx / H2_, h2 = idx % H2_;
        W2T[idx] = W2[h2 * H1_ + h1];
    }
    if (idx < H2_ * O_) {
        int h2 = idx / O_, o = idx % O_;
        WoT[idx] = Wo[o * H2_ + h2];
    }
    if (idx < H1_ * I_) {
        W1b[idx] = f2bf(W1[idx]);
    }
}

// ---------------------------------------------------------------------------
// K1: bf16 MFMA GEMM  din[m][n] = x[m,:] . W1[n,:] + b1[n]
//     M = cur*1024, N = 512, K = 256. Block tile 64x64, K staged in 2 halves.
// ---------------------------------------------------------------------------
__global__ __launch_bounds__(256) void gemm_mfma(
    const float* __restrict__ X,            // [M][256] f32
    const unsigned short* __restrict__ W1b, // [512][256] bf16
    const float* __restrict__ b1,
    float* __restrict__ out, int nwg)       // out [M][512]
{
    __shared__ unsigned short xs[64 * 128];
    __shared__ unsigned short w1s[64 * 128];

    // XCD-aware swizzle (nwg % 8 == 0), n-fastest within each XCD chunk
    int per = nwg >> 3;
    int bid = blockIdx.x;
    int logical = (bid & 7) * per + (bid >> 3);
    int m0 = (logical >> 3) * 64;
    int n0 = (logical & 7) * 64;

    int tid = threadIdx.x;
    int l  = tid & 63;
    int wv = tid >> 6;
    int wm = wv >> 1, wn = wv & 1;
    int lr = l & 15, lk = l >> 4;

    f4v acc[2][2] = {};

    for (int ks = 0; ks < 2; ks++) {
        #pragma unroll
        for (int it = 0; it < 4; it++) {
            int u = tid + it * 256;          // 0..1023
            int row = u >> 4, kb = u & 15;
            const float* xp = X + (size_t)(m0 + row) * I_ + ks * 128 + kb * 8;
            float4 v0 = *reinterpret_cast<const float4*>(xp);
            float4 v1 = *reinterpret_cast<const float4*>(xp + 4);
            us8v xv;
            xv[0] = f2bf(v0.x); xv[1] = f2bf(v0.y); xv[2] = f2bf(v0.z); xv[3] = f2bf(v0.w);
            xv[4] = f2bf(v1.x); xv[5] = f2bf(v1.y); xv[6] = f2bf(v1.z); xv[7] = f2bf(v1.w);
            int kbs = kb ^ (row & 7);
            *reinterpret_cast<us8v*>(&xs[(row << 7) + (kbs << 3)]) = xv;
            us8v wvv = *reinterpret_cast<const us8v*>(
                W1b + (size_t)(n0 + row) * I_ + ks * 128 + kb * 8);
            *reinterpret_cast<us8v*>(&w1s[(row << 7) + (kbs << 3)]) = wvv;
        }
        __syncthreads();
        #pragma unroll
        for (int kk = 0; kk < 4; kk++) {
            int kb = kk * 4 + lk;
            int ra0 = wm * 32 + lr, ra1 = ra0 + 16;
            int cb0 = wn * 32 + lr, cb1 = cb0 + 16;
            s8v a0 = *reinterpret_cast<const s8v*>(&xs[(ra0 << 7) + ((kb ^ (ra0 & 7)) << 3)]);
            s8v a1 = *reinterpret_cast<const s8v*>(&xs[(ra1 << 7) + ((kb ^ (ra1 & 7)) << 3)]);
            s8v b0 = *reinterpret_cast<const s8v*>(&w1s[(cb0 << 7) + ((kb ^ (cb0 & 7)) << 3)]);
            s8v b1v = *reinterpret_cast<const s8v*>(&w1s[(cb1 << 7) + ((kb ^ (cb1 & 7)) << 3)]);
            acc[0][0] = __builtin_amdgcn_mfma_f32_16x16x32_bf16(a0, b0,  acc[0][0], 0, 0, 0);
            acc[0][1] = __builtin_amdgcn_mfma_f32_16x16x32_bf16(a0, b1v, acc[0][1], 0, 0, 0);
            acc[1][0] = __builtin_amdgcn_mfma_f32_16x16x32_bf16(a1, b0,  acc[1][0], 0, 0, 0);
            acc[1][1] = __builtin_amdgcn_mfma_f32_16x16x32_bf16(a1, b1v, acc[1][1], 0, 0, 0);
        }
        __syncthreads();
    }

    float bia0 = b1[n0 + wn * 32 + lr];
    float bia1 = b1[n0 + wn * 32 + 16 + lr];
    #pragma unroll
    for (int mi = 0; mi < 2; mi++) {
        #pragma unroll
        for (int ni = 0; ni < 2; ni++) {
            float bb = ni ? bia1 : bia0;
            #pragma unroll
            for (int r = 0; r < 4; r++) {
                int row = m0 + wm * 32 + mi * 16 + lk * 4 + r;
                int col = n0 + wn * 32 + ni * 16 + lr;
                out[(size_t)row * H1_ + col] = acc[mi][ni][r] + bb;
            }
        }
    }
}

// ---------------------------------------------------------------------------
// K2: layer-1 chunk-parallel exact LIF scan.
// Block = (64 h) x (16 chunks) = 1024 threads; grid = (8 hg, cur b).
// ---------------------------------------------------------------------------
__global__ __launch_bounds__(1024) void scan1_kernel(
    const float* __restrict__ din,        // [cur][1024][512]
    const float* __restrict__ tau_m1, const float* __restrict__ tau_n1,
    u64* __restrict__ s1_bits, u64* __restrict__ s1_any, int b0)
{
    __shared__ float vd[CH_][64];
    __shared__ float meS[CH_][64];
    __shared__ float thS[CH_][64];
    __shared__ float memio[64];
    __shared__ int hdirty[64];
    __shared__ int anyd;

    int tid = threadIdx.x;
    int h = tid & 63, c = tid >> 6;
    int hg = blockIdx.x;
    int bl = blockIdx.y;
    int b  = b0 + bl;
    int hglob = hg * 64 + h;

    if (tid < 64) hdirty[tid] = 0;
    if (tid == 0) anyd = 0;

    float beta    = 1.f / (1.f + expf(-tau_n1[hglob]));
    float alpha   = 1.f / (1.f + expf(-tau_m1[hglob]));
    float ombeta  = 1.f - beta;
    float omalpha = 1.f - alpha;
    float bL = beta;  { bL *= bL; bL *= bL; bL *= bL; bL *= bL; bL *= bL; bL *= bL; }
    float aL = alpha; { aL *= aL; aL *= aL; aL *= aL; aL *= aL; aL *= aL; aL *= aL; }
    float ai = 1.0f / alpha;

    float arr[LL_];
    const float* p = din + ((size_t)bl * T_ + c * LL_) * H1_ + hglob;
    float d1 = 0.f;
    #pragma unroll
    for (int i = 0; i < LL_; i++) {
        float xv = p[i * H1_];
        d1 = fmaf(beta, d1, ombeta * xv);
        arr[i] = d1;
    }
    vd[c][h] = d1;
    __syncthreads();

    float ds = 0.f;
    for (int cc = 0; cc < c; cc++) ds = fmaf(bL, ds, vd[cc][h]);

    float pc = ds, m = 0.f, api = 1.f, th = 3.4e38f;
    #pragma unroll
    for (int i = 0; i < LL_; i++) {
        pc *= beta;
        float dt = arr[i] + pc;
        arr[i] = dt;
        m = fmaf(alpha, m, omalpha * dt);
        api *= ai;
        th = fminf(th, (1.f - m) * api);
    }
    meS[c][h] = m;
    thS[c][h] = th;
    __syncthreads();

    // optimistic stitch
    float v = 0.f; bool dirty = false;
    for (int cc = 0; cc < c; cc++) {
        if (v > thS[cc][h] - GUARD_) dirty = true;
        v = fmaf(aL, v, meS[cc][h]);
    }
    if (v > th - GUARD_) dirty = true;
    if (dirty) { hdirty[h] = 1; atomicOr(&anyd, 1); }
    __syncthreads();

    if (anyd) {
        for (int cc = 0; cc < CH_; cc++) {
            if (c == cc && hdirty[h]) {
                float mi_ = (cc == 0) ? 0.f : memio[h];
                float mo;
                if (mi_ > th - GUARD_) {
                    float mem = mi_;
                    #pragma unroll
                    for (int i = 0; i < LL_; i++) {
                        mem = fmaf(alpha, mem, omalpha * arr[i]);
                        if (mem > 1.f) {
                            atomicOr(&s1_bits[((size_t)b * T_ + cc * LL_ + i) * 8 + hg], 1ull << h);
                            atomicOr(&s1_any[b * 16 + cc], 1ull << i);
                            mem = 0.f;
                        }
                    }
                    mo = mem;
                } else {
                    mo = fmaf(aL, mi_, m);
                }
                memio[h] = mo;
            }
            __syncthreads();
        }
    }
}

// ---------------------------------------------------------------------------
// helper: gather layer-2 input contribution from spiking h1's (rare)
// ---------------------------------------------------------------------------
__device__ __noinline__ float gather_w2(const u64* __restrict__ w,
                                        const float* __restrict__ W2T, int hglob)
{
    float acc = 0.f;
    for (int q = 0; q < 8; q++) {
        u64 mq = w[q];
        while (mq) {
            int h1 = __ffsll((long long)mq) - 1;
            mq &= mq - 1;
            acc += W2T[(size_t)(q * 64 + h1) * H2_ + hglob];
        }
    }
    return acc;
}

// ---------------------------------------------------------------------------
// K3: layer-2 chunk-parallel exact LIF scan (input = b2 + sparse spikes).
// ---------------------------------------------------------------------------
__global__ __launch_bounds__(1024) void scan2_kernel(
    const float* __restrict__ W2T, const float* __restrict__ b2,
    const float* __restrict__ tau_m2, const float* __restrict__ tau_n2,
    const u64* __restrict__ s1_bits, const u64* __restrict__ s1_any,
    u64* __restrict__ s2_bits, u64* __restrict__ s2_any, int b0)
{
    __shared__ float vd[CH_][64];
    __shared__ float meS[CH_][64];
    __shared__ float thS[CH_][64];
    __shared__ float memio[64];
    __shared__ int hdirty[64];
    __shared__ int anyd;

    int tid = threadIdx.x;
    int h = tid & 63, c = tid >> 6;
    int hg = blockIdx.x;
    int b  = b0 + blockIdx.y;
    int hglob = hg * 64 + h;

    if (tid < 64) hdirty[tid] = 0;
    if (tid == 0) anyd = 0;

    float beta    = 1.f / (1.f + expf(-tau_n2[hglob]));
    float alpha   = 1.f / (1.f + expf(-tau_m2[hglob]));
    float ombeta  = 1.f - beta;
    float omalpha = 1.f - alpha;
    float bias    = b2[hglob];
    float bL = beta;  { bL *= bL; bL *= bL; bL *= bL; bL *= bL; bL *= bL; bL *= bL; }
    float aL = alpha; { aL *= aL; aL *= aL; aL *= aL; aL *= aL; aL *= aL; aL *= aL; }
    float ai = 1.0f / alpha;

    float arr[LL_];
    u64 aw = s1_any[b * 16 + c];
    float d2 = 0.f;
    if (aw == 0) {
        #pragma unroll
        for (int i = 0; i < LL_; i++) {
            d2 = fmaf(beta, d2, ombeta * bias);
            arr[i] = d2;
        }
    } else {
        #pragma unroll
        for (int i = 0; i < LL_; i++) {
            float dv = bias;
            if ((aw >> i) & 1ull)
                dv += gather_w2(s1_bits + ((size_t)b * T_ + c * LL_ + i) * 8, W2T, hglob);
            d2 = fmaf(beta, d2, ombeta * dv);
            arr[i] = d2;
        }
    }
    vd[c][h] = d2;
    __syncthreads();

    float ds = 0.f;
    for (int cc = 0; cc < c; cc++) ds = fmaf(bL, ds, vd[cc][h]);

    float pc = ds, m = 0.f, api = 1.f, th = 3.4e38f;
    #pragma unroll
    for (int i = 0; i < LL_; i++) {
        pc *= beta;
        float dt = arr[i] + pc;
        arr[i] = dt;
        m = fmaf(alpha, m, omalpha * dt);
        api *= ai;
        th = fminf(th, (1.f - m) * api);
    }
    meS[c][h] = m;
    thS[c][h] = th;
    __syncthreads();

    float v = 0.f; bool dirty = false;
    for (int cc = 0; cc < c; cc++) {
        if (v > thS[cc][h] - GUARD_) dirty = true;
        v = fmaf(aL, v, meS[cc][h]);
    }
    if (v > th - GUARD_) dirty = true;
    if (dirty) { hdirty[h] = 1; atomicOr(&anyd, 1); }
    __syncthreads();

    if (anyd) {
        for (int cc = 0; cc < CH_; cc++) {
            if (c == cc && hdirty[h]) {
                float mi_ = (cc == 0) ? 0.f : memio[h];
                float mo;
                if (mi_ > th - GUARD_) {
                    float mem = mi_;
                    #pragma unroll
                    for (int i = 0; i < LL_; i++) {
                        mem = fmaf(alpha, mem, omalpha * arr[i]);
                        if (mem > 1.f) {
                            atomicOr(&s2_bits[((size_t)b * T_ + cc * LL_ + i) * 8 + hg], 1ull << h);
                            atomicOr(&s2_any[b * 16 + cc], 1ull << i);
                            mem = 0.f;
                        }
                    }
                    mo = mem;
                } else {
                    mo = fmaf(aL, mi_, m);
                }
                memio[h] = mo;
            }
            __syncthreads();
        }
    }
}

// ---------------------------------------------------------------------------
// K4: output = sigmoid(bo + sum over spiking h2 of WoT[h2][:])
// ---------------------------------------------------------------------------
__global__ __launch_bounds__(256) void out_kernel(
    const float* __restrict__ WoT, const float* __restrict__ bo,
    const u64* __restrict__ s2_bits, const u64* __restrict__ s2_any,
    float* __restrict__ out, int b0)
{
    int idx = blockIdx.x * 256 + threadIdx.x;
    int o = idx & 127;
    int t = (idx >> 7) & 1023;
    int b = b0 + (idx >> 17);

    float z = bo[o];
    if ((s2_any[b * 16 + (t >> 6)] >> (t & 63)) & 1ull) {
        const u64* w = s2_bits + ((size_t)b * T_ + t) * 8;
        for (int q = 0; q < 8; q++) {
            u64 mq = w[q];
            while (mq) {
                int h2 = __ffsll((long long)mq) - 1;
                mq &= mq - 1;
                z += WoT[(size_t)(q * 64 + h2) * O_ + o];
            }
        }
    }
    out[((size_t)b * T_ + t) * O_ + o] = 1.f / (1.f + expf(-z));
}

// ---------------------------------------------------------------------------
// Launch
// ---------------------------------------------------------------------------
extern "C" void kernel_launch(void* const* d_in, const int* in_sizes, int n_in,
                              void* d_out, int out_size, void* d_ws, size_t ws_size,
                              hipStream_t stream)
{
    const float* x      = (const float*)d_in[0];
    const float* W1     = (const float*)d_in[1];
    const float* b1     = (const float*)d_in[2];
    const float* tau_m1 = (const float*)d_in[3];
    const float* tau_n1 = (const float*)d_in[4];
    const float* W2     = (const float*)d_in[5];
    const float* b2     = (const float*)d_in[6];
    const float* tau_m2 = (const float*)d_in[7];
    const float* tau_n2 = (const float*)d_in[8];
    const float* Wo     = (const float*)d_in[9];
    const float* bo     = (const float*)d_in[10];
    float* out = (float*)d_out;

    char* ws = (char*)d_ws;
    size_t off = 0;
    float* W2T = (float*)(ws + off);            off += (size_t)H1_ * H2_ * 4;   // 1 MB
    float* WoT = (float*)(ws + off);            off += (size_t)H2_ * O_ * 4;    // 256 KB
    unsigned short* W1b = (unsigned short*)(ws + off); off += (size_t)H1_ * I_ * 2; // 256 KB
    size_t zero_begin = off;
    u64* s1_any  = (u64*)(ws + off); off += (size_t)B_ * 16 * 8;
    u64* s2_any  = (u64*)(ws + off); off += (size_t)B_ * 16 * 8;
    u64* s1_bits = (u64*)(ws + off); off += (size_t)B_ * T_ * 8 * 8;            // 4 MB
    u64* s2_bits = (u64*)(ws + off); off += (size_t)B_ * T_ * 8 * 8;            // 4 MB
    size_t zero_bytes = off - zero_begin;
    float* din = (float*)(ws + off);
    size_t avail = (ws_size > off) ? (ws_size - off) : 0;
    const size_t per_b = (size_t)T_ * H1_ * 4;                                  // 2 MB
    int bchunk = (int)(avail / per_b);
    if (bchunk < 1) bchunk = 1;
    if (bchunk > B_) bchunk = B_;

    hipMemsetAsync(ws + zero_begin, 0, zero_bytes, stream);

    prep_kernel<<<dim3((H1_ * H2_ + 255) / 256), dim3(256), 0, stream>>>(
        W2, Wo, W1, W2T, WoT, W1b);

    for (int b0 = 0; b0 < B_; b0 += bchunk) {
        int cur = B_ - b0 < bchunk ? B_ - b0 : bchunk;
        int nwg = cur * 128;   // (M/64) * (N/64), divisible by 8

        gemm_mfma<<<dim3(nwg), dim3(256), 0, stream>>>(
            x + (size_t)b0 * T_ * I_, W1b, b1, din, nwg);

        scan1_kernel<<<dim3(8, cur), dim3(1024), 0, stream>>>(
            din, tau_m1, tau_n1, s1_bits, s1_any, b0);

        scan2_kernel<<<dim3(8, cur), dim3(1024), 0, stream>>>(
            W2T, b2, tau_m2, tau_n2, s1_bits, s1_any, s2_bits, s2_any, b0);

        out_kernel<<<dim3(cur * 512), dim3(256), 0, stream>>>(
            WoT, bo, s2_bits, s2_any, out, b0);
    }
}

// Round 5
// 242.840 us; speedup vs baseline: 2.9191x; 1.0386x over previous
//
#include <hip/hip_runtime.h>
#include <hip/hip_bf16.h>
#include <cstdint>

#define B_  64
#define T_  1024
#define I_  256
#define H1_ 512
#define H2_ 512
#define O_  128
#define CH_ 16
#define LL_ 64
#define GUARD_ 1e-3f

typedef unsigned long long u64;
typedef __attribute__((ext_vector_type(8))) short s8v;
typedef __attribute__((ext_vector_type(4))) float f4v;

__device__ __forceinline__ unsigned short f2bf(float f) {
    unsigned int u = __float_as_uint(f);
    unsigned int r = (u + 0x7FFFu + ((u >> 16) & 1u)) >> 16;
    return (unsigned short)r;
}

// ---------------------------------------------------------------------------
// Prep: W2 -> W2T, Wo -> WoT, W1 -> bf16
// ---------------------------------------------------------------------------
__global__ __launch_bounds__(256) void prep_kernel(
    const float* __restrict__ W2, const float* __restrict__ Wo,
    const float* __restrict__ W1,
    float* __restrict__ W2T, float* __restrict__ WoT,
    unsigned short* __restrict__ W1b)
{
    int idx = blockIdx.x * 256 + threadIdx.x;
    if (idx < H1_ * H2_) {
        int h1 = idx / H2_, h2 = idx % H2_;
        W2T[idx] = W2[h2 * H1_ + h1];
    }
    if (idx < H2_ * O_) {
        int h2 = idx / O_, o = idx % O_;
        WoT[idx] = Wo[o * H2_ + h2];
    }
    if (idx < H1_ * I_) {
        W1b[idx] = f2bf(W1[idx]);
    }
}

// ---------------------------------------------------------------------------
// Fused K1: bf16 MFMA GEMM (din tile in registers) + chunk-parallel LIF scan.
// Block = 1024 threads = 16 waves; wave c owns time-chunk c (64 steps).
// Grid = (8 h-groups, 64 b) = 512 blocks = 2 rounds of 1 block/CU.
// din never touches HBM.
// ---------------------------------------------------------------------------
__global__ __launch_bounds__(1024, 1) void fused1_kernel(
    const float* __restrict__ X,            // [B][1024][256] f32
    const unsigned short* __restrict__ W1b, // [512][256] bf16
    const float* __restrict__ b1,
    const float* __restrict__ tau_m1, const float* __restrict__ tau_n1,
    u64* __restrict__ s1_bits, u64* __restrict__ s1_any)
{
    __shared__ float rbuf[CH_][64][16];   // 64 KB: per-wave transpose buffers
    __shared__ float vd[CH_][64];
    __shared__ float meS[CH_][64];
    __shared__ float thS[CH_][64];
    __shared__ float memio[64];
    __shared__ int hdirty[64];
    __shared__ int anyd;

    const int tid = threadIdx.x;
    const int h  = tid & 63;        // lane = scan column within h-slice
    const int c  = tid >> 6;        // wave = time chunk
    const int hg = blockIdx.x;
    const int b  = blockIdx.y;
    const int n0 = hg * 64;
    const int lr = tid & 15;        // MFMA row/col lane index
    const int lq = (tid >> 4) & 3;  // MFMA k-group / D-row-group

    if (tid < 64) hdirty[tid] = 0;
    if (tid == 0) anyd = 0;

    // ---- GEMM: wave c computes din[t = c*64 ..][n0 ..+64] in MFMA frags ----
    // Verified mapping (round 4, absmax 0.0): A row=lr, k=lq*8+j; B col=lr,
    // k=lq*8+j; D col=lr, row=lq*4+r.
    f4v acc[4][4] = {};   // [mi][ni]
    const float* xb = X + ((size_t)b * T_ + c * LL_) * I_;
    #pragma unroll
    for (int ks = 0; ks < 8; ks++) {
        s8v bf[4];
        #pragma unroll
        for (int ni = 0; ni < 4; ni++)
            bf[ni] = *reinterpret_cast<const s8v*>(
                W1b + (size_t)(n0 + ni * 16 + lr) * I_ + ks * 32 + lq * 8);
        #pragma unroll
        for (int mi = 0; mi < 4; mi++) {
            const float* xp = xb + (size_t)(mi * 16 + lr) * I_ + ks * 32 + lq * 8;
            float4 v0 = *reinterpret_cast<const float4*>(xp);
            float4 v1 = *reinterpret_cast<const float4*>(xp + 4);
            // f32 -> bf16 round-half-up (cheap: add + shift)
            s8v a;
            a[0] = (short)((__float_as_uint(v0.x) + 0x8000u) >> 16);
            a[1] = (short)((__float_as_uint(v0.y) + 0x8000u) >> 16);
            a[2] = (short)((__float_as_uint(v0.z) + 0x8000u) >> 16);
            a[3] = (short)((__float_as_uint(v0.w) + 0x8000u) >> 16);
            a[4] = (short)((__float_as_uint(v1.x) + 0x8000u) >> 16);
            a[5] = (short)((__float_as_uint(v1.y) + 0x8000u) >> 16);
            a[6] = (short)((__float_as_uint(v1.z) + 0x8000u) >> 16);
            a[7] = (short)((__float_as_uint(v1.w) + 0x8000u) >> 16);
            #pragma unroll
            for (int ni = 0; ni < 4; ni++)
                acc[mi][ni] = __builtin_amdgcn_mfma_f32_16x16x32_bf16(
                    a, bf[ni], acc[mi][ni], 0, 0, 0);
        }
    }

    // ---- intra-wave transpose: MFMA layout -> scan layout (arr[64]) ----
    // phys quad = logical quad ^ swz(col), swz(col) = (col&3)^((col>>2)&3):
    // both write and read spread evenly over all 8 bank-quads.
    const float biasv = b1[n0 + h];
    const int swz_w = (lr & 3) ^ (lr >> 2);          // = swz(ni*16+lr), ni-indep
    const int swz_r = (h & 3) ^ ((h >> 2) & 3);
    float arr[LL_];
    #pragma unroll
    for (int mi = 0; mi < 4; mi++) {
        #pragma unroll
        for (int ni = 0; ni < 4; ni++) {
            *reinterpret_cast<float4*>(&rbuf[c][ni * 16 + lr][(lq ^ swz_w) * 4]) =
                make_float4(acc[mi][ni][0], acc[mi][ni][1],
                            acc[mi][ni][2], acc[mi][ni][3]);
        }
        __builtin_amdgcn_wave_barrier();
        #pragma unroll
        for (int jq = 0; jq < 4; jq++) {
            float4 rv = *reinterpret_cast<const float4*>(&rbuf[c][h][(jq ^ swz_r) * 4]);
            arr[mi * 16 + jq * 4 + 0] = rv.x + biasv;
            arr[mi * 16 + jq * 4 + 1] = rv.y + biasv;
            arr[mi * 16 + jq * 4 + 2] = rv.z + biasv;
            arr[mi * 16 + jq * 4 + 3] = rv.w + biasv;
        }
        __builtin_amdgcn_wave_barrier();
    }

    // ---- chunk-parallel exact LIF scan (identical to verified scan1) ----
    const int hglob = n0 + h;
    float beta    = 1.f / (1.f + expf(-tau_n1[hglob]));
    float alpha   = 1.f / (1.f + expf(-tau_m1[hglob]));
    float ombeta  = 1.f - beta;
    float omalpha = 1.f - alpha;
    float bL = beta;  { bL *= bL; bL *= bL; bL *= bL; bL *= bL; bL *= bL; bL *= bL; }
    float aL = alpha; { aL *= aL; aL *= aL; aL *= aL; aL *= aL; aL *= aL; aL *= aL; }
    float ai = 1.0f / alpha;

    float d1 = 0.f;
    #pragma unroll
    for (int i = 0; i < LL_; i++) {
        d1 = fmaf(beta, d1, ombeta * arr[i]);   // arr holds din
        arr[i] = d1;                            // -> d partials (0-init)
    }
    vd[c][h] = d1;
    __syncthreads();

    float ds = 0.f;
    for (int cc = 0; cc < c; cc++) ds = fmaf(bL, ds, vd[cc][h]);

    float pc = ds, m = 0.f, api = 1.f, th = 3.4e38f;
    #pragma unroll
    for (int i = 0; i < LL_; i++) {
        pc *= beta;
        float dt = arr[i] + pc;                 // exact d
        arr[i] = dt;
        m = fmaf(alpha, m, omalpha * dt);
        api *= ai;
        th = fminf(th, (1.f - m) * api);
    }
    meS[c][h] = m;
    thS[c][h] = th;
    __syncthreads();

    // optimistic no-spike stitch
    float v = 0.f; bool dirty = false;
    for (int cc = 0; cc < c; cc++) {
        if (v > thS[cc][h] - GUARD_) dirty = true;
        v = fmaf(aL, v, meS[cc][h]);
    }
    if (v > th - GUARD_) dirty = true;
    if (dirty) { hdirty[h] = 1; atomicOr(&anyd, 1); }
    __syncthreads();

    if (anyd) {
        for (int cc = 0; cc < CH_; cc++) {
            if (c == cc && hdirty[h]) {
                float mi_ = (cc == 0) ? 0.f : memio[h];
                float mo;
                if (mi_ > th - GUARD_) {
                    float mem = mi_;
                    #pragma unroll
                    for (int i = 0; i < LL_; i++) {
                        mem = fmaf(alpha, mem, omalpha * arr[i]);
                        if (mem > 1.f) {
                            atomicOr(&s1_bits[((size_t)b * T_ + cc * LL_ + i) * 8 + hg], 1ull << h);
                            atomicOr(&s1_any[b * 16 + cc], 1ull << i);
                            mem = 0.f;
                        }
                    }
                    mo = mem;
                } else {
                    mo = fmaf(aL, mi_, m);
                }
                memio[h] = mo;
            }
            __syncthreads();
        }
    }
}

// ---------------------------------------------------------------------------
// helper: gather layer-2 input contribution from spiking h1's (rare)
// ---------------------------------------------------------------------------
__device__ __noinline__ float gather_w2(const u64* __restrict__ w,
                                        const float* __restrict__ W2T, int hglob)
{
    float acc = 0.f;
    for (int q = 0; q < 8; q++) {
        u64 mq = w[q];
        while (mq) {
            int h1 = __ffsll((long long)mq) - 1;
            mq &= mq - 1;
            acc += W2T[(size_t)(q * 64 + h1) * H2_ + hglob];
        }
    }
    return acc;
}

// ---------------------------------------------------------------------------
// K3: layer-2 chunk-parallel exact LIF scan (input = b2 + sparse spikes).
// ---------------------------------------------------------------------------
__global__ __launch_bounds__(1024) void scan2_kernel(
    const float* __restrict__ W2T, const float* __restrict__ b2,
    const float* __restrict__ tau_m2, const float* __restrict__ tau_n2,
    const u64* __restrict__ s1_bits, const u64* __restrict__ s1_any,
    u64* __restrict__ s2_bits, u64* __restrict__ s2_any)
{
    __shared__ float vd[CH_][64];
    __shared__ float meS[CH_][64];
    __shared__ float thS[CH_][64];
    __shared__ float memio[64];
    __shared__ int hdirty[64];
    __shared__ int anyd;

    int tid = threadIdx.x;
    int h = tid & 63, c = tid >> 6;
    int hg = blockIdx.x;
    int b  = blockIdx.y;
    int hglob = hg * 64 + h;

    if (tid < 64) hdirty[tid] = 0;
    if (tid == 0) anyd = 0;

    float beta    = 1.f / (1.f + expf(-tau_n2[hglob]));
    float alpha   = 1.f / (1.f + expf(-tau_m2[hglob]));
    float ombeta  = 1.f - beta;
    float omalpha = 1.f - alpha;
    float bias    = b2[hglob];
    float bL = beta;  { bL *= bL; bL *= bL; bL *= bL; bL *= bL; bL *= bL; bL *= bL; }
    float aL = alpha; { aL *= aL; aL *= aL; aL *= aL; aL *= aL; aL *= aL; aL *= aL; }
    float ai = 1.0f / alpha;

    float arr[LL_];
    u64 aw = s1_any[b * 16 + c];
    float d2 = 0.f;
    if (aw == 0) {
        #pragma unroll
        for (int i = 0; i < LL_; i++) {
            d2 = fmaf(beta, d2, ombeta * bias);
            arr[i] = d2;
        }
    } else {
        #pragma unroll
        for (int i = 0; i < LL_; i++) {
            float dv = bias;
            if ((aw >> i) & 1ull)
                dv += gather_w2(s1_bits + ((size_t)b * T_ + c * LL_ + i) * 8, W2T, hglob);
            d2 = fmaf(beta, d2, ombeta * dv);
            arr[i] = d2;
        }
    }
    vd[c][h] = d2;
    __syncthreads();

    float ds = 0.f;
    for (int cc = 0; cc < c; cc++) ds = fmaf(bL, ds, vd[cc][h]);

    float pc = ds, m = 0.f, api = 1.f, th = 3.4e38f;
    #pragma unroll
    for (int i = 0; i < LL_; i++) {
        pc *= beta;
        float dt = arr[i] + pc;
        arr[i] = dt;
        m = fmaf(alpha, m, omalpha * dt);
        api *= ai;
        th = fminf(th, (1.f - m) * api);
    }
    meS[c][h] = m;
    thS[c][h] = th;
    __syncthreads();

    float v = 0.f; bool dirty = false;
    for (int cc = 0; cc < c; cc++) {
        if (v > thS[cc][h] - GUARD_) dirty = true;
        v = fmaf(aL, v, meS[cc][h]);
    }
    if (v > th - GUARD_) dirty = true;
    if (dirty) { hdirty[h] = 1; atomicOr(&anyd, 1); }
    __syncthreads();

    if (anyd) {
        for (int cc = 0; cc < CH_; cc++) {
            if (c == cc && hdirty[h]) {
                float mi_ = (cc == 0) ? 0.f : memio[h];
                float mo;
                if (mi_ > th - GUARD_) {
                    float mem = mi_;
                    #pragma unroll
                    for (int i = 0; i < LL_; i++) {
                        mem = fmaf(alpha, mem, omalpha * arr[i]);
                        if (mem > 1.f) {
                            atomicOr(&s2_bits[((size_t)b * T_ + cc * LL_ + i) * 8 + hg], 1ull << h);
                            atomicOr(&s2_any[b * 16 + cc], 1ull << i);
                            mem = 0.f;
                        }
                    }
                    mo = mem;
                } else {
                    mo = fmaf(aL, mi_, m);
                }
                memio[h] = mo;
            }
            __syncthreads();
        }
    }
}

// ---------------------------------------------------------------------------
// K4: output = sigmoid(bo + sum over spiking h2 of WoT[h2][:])
// ---------------------------------------------------------------------------
__global__ __launch_bounds__(256) void out_kernel(
    const float* __restrict__ WoT, const float* __restrict__ bo,
    const u64* __restrict__ s2_bits, const u64* __restrict__ s2_any,
    float* __restrict__ out)
{
    int idx = blockIdx.x * 256 + threadIdx.x;
    int o = idx & 127;
    int t = (idx >> 7) & 1023;
    int b = idx >> 17;

    float z = bo[o];
    if ((s2_any[b * 16 + (t >> 6)] >> (t & 63)) & 1ull) {
        const u64* w = s2_bits + ((size_t)b * T_ + t) * 8;
        for (int q = 0; q < 8; q++) {
            u64 mq = w[q];
            while (mq) {
                int h2 = __ffsll((long long)mq) - 1;
                mq &= mq - 1;
                z += WoT[(size_t)(q * 64 + h2) * O_ + o];
            }
        }
    }
    out[((size_t)b * T_ + t) * O_ + o] = 1.f / (1.f + expf(-z));
}

// ---------------------------------------------------------------------------
// Launch
// ---------------------------------------------------------------------------
extern "C" void kernel_launch(void* const* d_in, const int* in_sizes, int n_in,
                              void* d_out, int out_size, void* d_ws, size_t ws_size,
                              hipStream_t stream)
{
    const float* x      = (const float*)d_in[0];
    const float* W1     = (const float*)d_in[1];
    const float* b1     = (const float*)d_in[2];
    const float* tau_m1 = (const float*)d_in[3];
    const float* tau_n1 = (const float*)d_in[4];
    const float* W2     = (const float*)d_in[5];
    const float* b2     = (const float*)d_in[6];
    const float* tau_m2 = (const float*)d_in[7];
    const float* tau_n2 = (const float*)d_in[8];
    const float* Wo     = (const float*)d_in[9];
    const float* bo     = (const float*)d_in[10];
    float* out = (float*)d_out;

    char* ws = (char*)d_ws;
    size_t off = 0;
    float* W2T = (float*)(ws + off);            off += (size_t)H1_ * H2_ * 4;   // 1 MB
    float* WoT = (float*)(ws + off);            off += (size_t)H2_ * O_ * 4;    // 256 KB
    unsigned short* W1b = (unsigned short*)(ws + off); off += (size_t)H1_ * I_ * 2; // 256 KB
    size_t zero_begin = off;
    u64* s1_any  = (u64*)(ws + off); off += (size_t)B_ * 16 * 8;
    u64* s2_any  = (u64*)(ws + off); off += (size_t)B_ * 16 * 8;
    u64* s1_bits = (u64*)(ws + off); off += (size_t)B_ * T_ * 8 * 8;            // 4 MB
    u64* s2_bits = (u64*)(ws + off); off += (size_t)B_ * T_ * 8 * 8;            // 4 MB
    size_t zero_bytes = off - zero_begin;

    hipMemsetAsync(ws + zero_begin, 0, zero_bytes, stream);

    prep_kernel<<<dim3((H1_ * H2_ + 255) / 256), dim3(256), 0, stream>>>(
        W2, Wo, W1, W2T, WoT, W1b);

    fused1_kernel<<<dim3(8, B_), dim3(1024), 0, stream>>>(
        x, W1b, b1, tau_m1, tau_n1, s1_bits, s1_any);

    scan2_kernel<<<dim3(8, B_), dim3(1024), 0, stream>>>(
        W2T, b2, tau_m2, tau_n2, s1_bits, s1_any, s2_bits, s2_any);

    out_kernel<<<dim3(B_ * 512), dim3(256), 0, stream>>>(
        WoT, bo, s2_bits, s2_any, out);
}

// Round 6
// 232.455 us; speedup vs baseline: 3.0495x; 1.0447x over previous
//
#include <hip/hip_runtime.h>
#include <hip/hip_bf16.h>
#include <cstdint>

#define B_  64
#define T_  1024
#define I_  256
#define H1_ 512
#define H2_ 512
#define O_  128
#define CH_ 16
#define LL_ 64
#define GUARD_ 1e-3f

typedef unsigned long long u64;
typedef __attribute__((ext_vector_type(8))) short s8v;
typedef __attribute__((ext_vector_type(4))) float f4v;

__device__ __forceinline__ unsigned short f2bf(float f) {
    unsigned int u = __float_as_uint(f);
    unsigned int r = (u + 0x7FFFu + ((u >> 16) & 1u)) >> 16;
    return (unsigned short)r;
}

// ---------------------------------------------------------------------------
// Prep: W2 -> W2T, Wo -> WoT, W1 -> bf16, zero spike buffers (replaces memset)
// ---------------------------------------------------------------------------
__global__ __launch_bounds__(256) void prep_kernel(
    const float* __restrict__ W2, const float* __restrict__ Wo,
    const float* __restrict__ W1,
    float* __restrict__ W2T, float* __restrict__ WoT,
    unsigned short* __restrict__ W1b,
    u64* __restrict__ zbuf, int nwords)
{
    int idx = blockIdx.x * 256 + threadIdx.x;
    if (idx < H1_ * H2_) {
        int h1 = idx / H2_, h2 = idx % H2_;
        W2T[idx] = W2[h2 * H1_ + h1];
    }
    if (idx < H2_ * O_) {
        int h2 = idx / O_, o = idx % O_;
        WoT[idx] = Wo[o * H2_ + h2];
    }
    if (idx < H1_ * I_) {
        W1b[idx] = f2bf(W1[idx]);
    }
    for (int i = idx; i < nwords; i += 256 * 1024)
        zbuf[i] = 0ull;
}

// ---------------------------------------------------------------------------
// Fused K1: bf16 MFMA GEMM (din tile in registers) + chunk-parallel LIF scan.
// Block = 1024 threads = 16 waves; wave c owns time-chunk c (64 steps).
// 1-D grid of 512: b = id&63, hg = id>>6  ->  id%8 = b%8, so all 8 hg-blocks
// of one batch land on the SAME XCD and share its L2 copy of x[b] (round 5
// had hg on id%8: 8 XCDs each fetched x[b] privately -> FETCH 267 MB).
// ---------------------------------------------------------------------------
__global__ __launch_bounds__(1024, 1) void fused1_kernel(
    const float* __restrict__ X,            // [B][1024][256] f32
    const unsigned short* __restrict__ W1b, // [512][256] bf16
    const float* __restrict__ b1,
    const float* __restrict__ tau_m1, const float* __restrict__ tau_n1,
    u64* __restrict__ s1_bits, u64* __restrict__ s1_any)
{
    __shared__ float rbuf[CH_][64][16];   // 64 KB: per-wave transpose buffers
    __shared__ float vd[CH_][64];
    __shared__ float meS[CH_][64];
    __shared__ float thS[CH_][64];
    __shared__ float memio[64];
    __shared__ int hdirty[64];
    __shared__ int anyd;

    const int tid = threadIdx.x;
    const int h  = tid & 63;        // lane = scan column within h-slice
    const int c  = tid >> 6;        // wave = time chunk
    const int id = blockIdx.x;
    const int b  = id & 63;
    const int hg = id >> 6;
    const int n0 = hg * 64;
    const int lr = tid & 15;        // MFMA row/col lane index
    const int lq = (tid >> 4) & 3;  // MFMA k-group / D-row-group

    if (tid < 64) hdirty[tid] = 0;
    if (tid == 0) anyd = 0;

    // ---- GEMM: wave c computes din[t = c*64 ..][n0 ..+64] in MFMA frags ----
    // Verified mapping (round 4/5, absmax 0.0): A row=lr, k=lq*8+j; B col=lr,
    // k=lq*8+j; D col=lr, row=lq*4+r.
    f4v acc[4][4] = {};   // [mi][ni]
    const float* xb = X + ((size_t)b * T_ + c * LL_) * I_;
    #pragma unroll
    for (int ks = 0; ks < 8; ks++) {
        s8v bf[4];
        #pragma unroll
        for (int ni = 0; ni < 4; ni++)
            bf[ni] = *reinterpret_cast<const s8v*>(
                W1b + (size_t)(n0 + ni * 16 + lr) * I_ + ks * 32 + lq * 8);
        #pragma unroll
        for (int mi = 0; mi < 4; mi++) {
            const float* xp = xb + (size_t)(mi * 16 + lr) * I_ + ks * 32 + lq * 8;
            float4 v0 = *reinterpret_cast<const float4*>(xp);
            float4 v1 = *reinterpret_cast<const float4*>(xp + 4);
            // f32 -> bf16 round-half-up (cheap: add + shift)
            s8v a;
            a[0] = (short)((__float_as_uint(v0.x) + 0x8000u) >> 16);
            a[1] = (short)((__float_as_uint(v0.y) + 0x8000u) >> 16);
            a[2] = (short)((__float_as_uint(v0.z) + 0x8000u) >> 16);
            a[3] = (short)((__float_as_uint(v0.w) + 0x8000u) >> 16);
            a[4] = (short)((__float_as_uint(v1.x) + 0x8000u) >> 16);
            a[5] = (short)((__float_as_uint(v1.y) + 0x8000u) >> 16);
            a[6] = (short)((__float_as_uint(v1.z) + 0x8000u) >> 16);
            a[7] = (short)((__float_as_uint(v1.w) + 0x8000u) >> 16);
            #pragma unroll
            for (int ni = 0; ni < 4; ni++)
                acc[mi][ni] = __builtin_amdgcn_mfma_f32_16x16x32_bf16(
                    a, bf[ni], acc[mi][ni], 0, 0, 0);
        }
    }

    // ---- intra-wave transpose: MFMA layout -> scan layout (arr[64]) ----
    const float biasv = b1[n0 + h];
    const int swz_w = (lr & 3) ^ (lr >> 2);
    const int swz_r = (h & 3) ^ ((h >> 2) & 3);
    float arr[LL_];
    #pragma unroll
    for (int mi = 0; mi < 4; mi++) {
        #pragma unroll
        for (int ni = 0; ni < 4; ni++) {
            *reinterpret_cast<float4*>(&rbuf[c][ni * 16 + lr][(lq ^ swz_w) * 4]) =
                make_float4(acc[mi][ni][0], acc[mi][ni][1],
                            acc[mi][ni][2], acc[mi][ni][3]);
        }
        __builtin_amdgcn_wave_barrier();
        #pragma unroll
        for (int jq = 0; jq < 4; jq++) {
            float4 rv = *reinterpret_cast<const float4*>(&rbuf[c][h][(jq ^ swz_r) * 4]);
            arr[mi * 16 + jq * 4 + 0] = rv.x + biasv;
            arr[mi * 16 + jq * 4 + 1] = rv.y + biasv;
            arr[mi * 16 + jq * 4 + 2] = rv.z + biasv;
            arr[mi * 16 + jq * 4 + 3] = rv.w + biasv;
        }
        __builtin_amdgcn_wave_barrier();
    }

    // ---- chunk-parallel exact LIF scan ----
    const int hglob = n0 + h;
    float beta    = 1.f / (1.f + __expf(-tau_n1[hglob]));
    float alpha   = 1.f / (1.f + __expf(-tau_m1[hglob]));
    float ombeta  = 1.f - beta;
    float omalpha = 1.f - alpha;
    float bL = beta;  { bL *= bL; bL *= bL; bL *= bL; bL *= bL; bL *= bL; bL *= bL; }
    float aL = alpha; { aL *= aL; aL *= aL; aL *= aL; aL *= aL; aL *= aL; aL *= aL; }
    float ai = 1.0f / alpha;

    float d1 = 0.f;
    #pragma unroll
    for (int i = 0; i < LL_; i++) {
        d1 = fmaf(beta, d1, ombeta * arr[i]);
        arr[i] = d1;
    }
    vd[c][h] = d1;
    __syncthreads();

    float ds = 0.f;
    for (int cc = 0; cc < c; cc++) ds = fmaf(bL, ds, vd[cc][h]);

    float pc = ds, m = 0.f, api = 1.f, th = 3.4e38f;
    #pragma unroll
    for (int i = 0; i < LL_; i++) {
        pc *= beta;
        float dt = arr[i] + pc;
        arr[i] = dt;
        m = fmaf(alpha, m, omalpha * dt);
        api *= ai;
        th = fminf(th, (1.f - m) * api);
    }
    meS[c][h] = m;
    thS[c][h] = th;
    __syncthreads();

    float v = 0.f; bool dirty = false;
    for (int cc = 0; cc < c; cc++) {
        if (v > thS[cc][h] - GUARD_) dirty = true;
        v = fmaf(aL, v, meS[cc][h]);
    }
    if (v > th - GUARD_) dirty = true;
    if (dirty) { hdirty[h] = 1; atomicOr(&anyd, 1); }
    __syncthreads();

    if (anyd) {
        for (int cc = 0; cc < CH_; cc++) {
            if (c == cc && hdirty[h]) {
                float mi_ = (cc == 0) ? 0.f : memio[h];
                float mo;
                if (mi_ > th - GUARD_) {
                    float mem = mi_;
                    #pragma unroll
                    for (int i = 0; i < LL_; i++) {
                        mem = fmaf(alpha, mem, omalpha * arr[i]);
                        if (mem > 1.f) {
                            atomicOr(&s1_bits[((size_t)b * T_ + cc * LL_ + i) * 8 + hg], 1ull << h);
                            atomicOr(&s1_any[b * 16 + cc], 1ull << i);
                            mem = 0.f;
                        }
                    }
                    mo = mem;
                } else {
                    mo = fmaf(aL, mi_, m);
                }
                memio[h] = mo;
            }
            __syncthreads();
        }
    }
}

// ---------------------------------------------------------------------------
// helper: gather layer-2 input contribution from spiking h1's (rare)
// ---------------------------------------------------------------------------
__device__ __noinline__ float gather_w2(const u64* __restrict__ w,
                                        const float* __restrict__ W2T, int hglob)
{
    float acc = 0.f;
    for (int q = 0; q < 8; q++) {
        u64 mq = w[q];
        while (mq) {
            int h1 = __ffsll((long long)mq) - 1;
            mq &= mq - 1;
            acc += W2T[(size_t)(q * 64 + h1) * H2_ + hglob];
        }
    }
    return acc;
}

// ---------------------------------------------------------------------------
// K3: layer-2 chunk-parallel exact LIF scan (input = b2 + sparse spikes).
// ---------------------------------------------------------------------------
__global__ __launch_bounds__(1024) void scan2_kernel(
    const float* __restrict__ W2T, const float* __restrict__ b2,
    const float* __restrict__ tau_m2, const float* __restrict__ tau_n2,
    const u64* __restrict__ s1_bits, const u64* __restrict__ s1_any,
    u64* __restrict__ s2_bits, u64* __restrict__ s2_any)
{
    __shared__ float vd[CH_][64];
    __shared__ float meS[CH_][64];
    __shared__ float thS[CH_][64];
    __shared__ float memio[64];
    __shared__ int hdirty[64];
    __shared__ int anyd;

    int tid = threadIdx.x;
    int h = tid & 63, c = tid >> 6;
    int id = blockIdx.x;
    int b  = id & 63;
    int hg = id >> 6;
    int hglob = hg * 64 + h;

    if (tid < 64) hdirty[tid] = 0;
    if (tid == 0) anyd = 0;

    float beta    = 1.f / (1.f + __expf(-tau_n2[hglob]));
    float alpha   = 1.f / (1.f + __expf(-tau_m2[hglob]));
    float ombeta  = 1.f - beta;
    float omalpha = 1.f - alpha;
    float bias    = b2[hglob];
    float bL = beta;  { bL *= bL; bL *= bL; bL *= bL; bL *= bL; bL *= bL; bL *= bL; }
    float aL = alpha; { aL *= aL; aL *= aL; aL *= aL; aL *= aL; aL *= aL; aL *= aL; }
    float ai = 1.0f / alpha;

    float arr[LL_];
    u64 aw = s1_any[b * 16 + c];
    float d2 = 0.f;
    if (aw == 0) {
        #pragma unroll
        for (int i = 0; i < LL_; i++) {
            d2 = fmaf(beta, d2, ombeta * bias);
            arr[i] = d2;
        }
    } else {
        #pragma unroll
        for (int i = 0; i < LL_; i++) {
            float dv = bias;
            if ((aw >> i) & 1ull)
                dv += gather_w2(s1_bits + ((size_t)b * T_ + c * LL_ + i) * 8, W2T, hglob);
            d2 = fmaf(beta, d2, ombeta * dv);
            arr[i] = d2;
        }
    }
    vd[c][h] = d2;
    __syncthreads();

    float ds = 0.f;
    for (int cc = 0; cc < c; cc++) ds = fmaf(bL, ds, vd[cc][h]);

    float pc = ds, m = 0.f, api = 1.f, th = 3.4e38f;
    #pragma unroll
    for (int i = 0; i < LL_; i++) {
        pc *= beta;
        float dt = arr[i] + pc;
        arr[i] = dt;
        m = fmaf(alpha, m, omalpha * dt);
        api *= ai;
        th = fminf(th, (1.f - m) * api);
    }
    meS[c][h] = m;
    thS[c][h] = th;
    __syncthreads();

    float v = 0.f; bool dirty = false;
    for (int cc = 0; cc < c; cc++) {
        if (v > thS[cc][h] - GUARD_) dirty = true;
        v = fmaf(aL, v, meS[cc][h]);
    }
    if (v > th - GUARD_) dirty = true;
    if (dirty) { hdirty[h] = 1; atomicOr(&anyd, 1); }
    __syncthreads();

    if (anyd) {
        for (int cc = 0; cc < CH_; cc++) {
            if (c == cc && hdirty[h]) {
                float mi_ = (cc == 0) ? 0.f : memio[h];
                float mo;
                if (mi_ > th - GUARD_) {
                    float mem = mi_;
                    #pragma unroll
                    for (int i = 0; i < LL_; i++) {
                        mem = fmaf(alpha, mem, omalpha * arr[i]);
                        if (mem > 1.f) {
                            atomicOr(&s2_bits[((size_t)b * T_ + cc * LL_ + i) * 8 + hg], 1ull << h);
                            atomicOr(&s2_any[b * 16 + cc], 1ull << i);
                            mem = 0.f;
                        }
                    }
                    mo = mem;
                } else {
                    mo = fmaf(aL, mi_, m);
                }
                memio[h] = mo;
            }
            __syncthreads();
        }
    }
}

// ---------------------------------------------------------------------------
// K4: output = sigmoid(bo + sum over spiking h2 of WoT[h2][:]), float4 stores
// ---------------------------------------------------------------------------
__global__ __launch_bounds__(256) void out_kernel(
    const float* __restrict__ WoT, const float* __restrict__ bo,
    const u64* __restrict__ s2_bits, const u64* __restrict__ s2_any,
    float* __restrict__ out)
{
    int idx = blockIdx.x * 256 + threadIdx.x;
    int o4 = idx & 31;                 // float4 group within O=128
    int t  = (idx >> 5) & 1023;
    int b  = idx >> 15;

    float4 z = *reinterpret_cast<const float4*>(bo + o4 * 4);
    if ((s2_any[b * 16 + (t >> 6)] >> (t & 63)) & 1ull) {
        const u64* w = s2_bits + ((size_t)b * T_ + t) * 8;
        for (int q = 0; q < 8; q++) {
            u64 mq = w[q];
            while (mq) {
                int h2 = __ffsll((long long)mq) - 1;
                mq &= mq - 1;
                float4 wv = *reinterpret_cast<const float4*>(
                    WoT + (size_t)(q * 64 + h2) * O_ + o4 * 4);
                z.x += wv.x; z.y += wv.y; z.z += wv.z; z.w += wv.w;
            }
        }
    }
    float4 r;
    r.x = 1.f / (1.f + __expf(-z.x));
    r.y = 1.f / (1.f + __expf(-z.y));
    r.z = 1.f / (1.f + __expf(-z.z));
    r.w = 1.f / (1.f + __expf(-z.w));
    *reinterpret_cast<float4*>(out + ((size_t)b * T_ + t) * O_ + o4 * 4) = r;
}

// ---------------------------------------------------------------------------
// Launch
// ---------------------------------------------------------------------------
extern "C" void kernel_launch(void* const* d_in, const int* in_sizes, int n_in,
                              void* d_out, int out_size, void* d_ws, size_t ws_size,
                              hipStream_t stream)
{
    const float* x      = (const float*)d_in[0];
    const float* W1     = (const float*)d_in[1];
    const float* b1     = (const float*)d_in[2];
    const float* tau_m1 = (const float*)d_in[3];
    const float* tau_n1 = (const float*)d_in[4];
    const float* W2     = (const float*)d_in[5];
    const float* b2     = (const float*)d_in[6];
    const float* tau_m2 = (const float*)d_in[7];
    const float* tau_n2 = (const float*)d_in[8];
    const float* Wo     = (const float*)d_in[9];
    const float* bo     = (const float*)d_in[10];
    float* out = (float*)d_out;

    char* ws = (char*)d_ws;
    size_t off = 0;
    float* W2T = (float*)(ws + off);            off += (size_t)H1_ * H2_ * 4;   // 1 MB
    float* WoT = (float*)(ws + off);            off += (size_t)H2_ * O_ * 4;    // 256 KB
    unsigned short* W1b = (unsigned short*)(ws + off); off += (size_t)H1_ * I_ * 2; // 256 KB
    size_t zero_begin = off;
    u64* s1_any  = (u64*)(ws + off); off += (size_t)B_ * 16 * 8;
    u64* s2_any  = (u64*)(ws + off); off += (size_t)B_ * 16 * 8;
    u64* s1_bits = (u64*)(ws + off); off += (size_t)B_ * T_ * 8 * 8;            // 4 MB
    u64* s2_bits = (u64*)(ws + off); off += (size_t)B_ * T_ * 8 * 8;            // 4 MB
    int zero_words = (int)((off - zero_begin) / 8);

    prep_kernel<<<dim3(1024), dim3(256), 0, stream>>>(
        W2, Wo, W1, W2T, WoT, W1b, (u64*)(ws + zero_begin), zero_words);

    fused1_kernel<<<dim3(512), dim3(1024), 0, stream>>>(
        x, W1b, b1, tau_m1, tau_n1, s1_bits, s1_any);

    scan2_kernel<<<dim3(512), dim3(1024), 0, stream>>>(
        W2T, b2, tau_m2, tau_n2, s1_bits, s1_any, s2_bits, s2_any);

    out_kernel<<<dim3(B_ * 128), dim3(256), 0, stream>>>(
        WoT, bo, s2_bits, s2_any, out);
}

// Round 7
// 190.635 us; speedup vs baseline: 3.7184x; 1.2194x over previous
//
#include <hip/hip_runtime.h>
#include <hip/hip_bf16.h>
#include <cstdint>

#define B_  64
#define T_  1024
#define I_  256
#define H1_ 512
#define H2_ 512
#define O_  128
#define CH_ 16
#define LL_ 64
#define GUARD_ 1e-3f

typedef unsigned long long u64;
typedef __attribute__((ext_vector_type(8))) short s8v;
typedef __attribute__((ext_vector_type(4))) float f4v;
typedef __attribute__((ext_vector_type(8))) unsigned short us8v;

__device__ __forceinline__ unsigned short f2bf(float f) {          // RNE-ish (weights)
    unsigned int u = __float_as_uint(f);
    return (unsigned short)((u + 0x7FFFu + ((u >> 16) & 1u)) >> 16);
}
__device__ __forceinline__ unsigned short f2bf_rhu(float f) {      // round-half-up (x path)
    return (unsigned short)((__float_as_uint(f) + 0x8000u) >> 16);
}

// ---------------------------------------------------------------------------
// K0: x f32 -> bf16 (streaming, 8 elem/thread)
// ---------------------------------------------------------------------------
__global__ __launch_bounds__(256) void xcvt_kernel(
    const float* __restrict__ X, unsigned short* __restrict__ Xb)
{
    size_t i = ((size_t)blockIdx.x * 256 + threadIdx.x) * 8;
    float4 v0 = *reinterpret_cast<const float4*>(X + i);
    float4 v1 = *reinterpret_cast<const float4*>(X + i + 4);
    us8v r;
    r[0] = f2bf_rhu(v0.x); r[1] = f2bf_rhu(v0.y);
    r[2] = f2bf_rhu(v0.z); r[3] = f2bf_rhu(v0.w);
    r[4] = f2bf_rhu(v1.x); r[5] = f2bf_rhu(v1.y);
    r[6] = f2bf_rhu(v1.z); r[7] = f2bf_rhu(v1.w);
    *reinterpret_cast<us8v*>(Xb + i) = r;
}

// ---------------------------------------------------------------------------
// Prep: W2 -> W2T, Wo -> WoT, W1 -> bf16, zero spike buffers
// ---------------------------------------------------------------------------
__global__ __launch_bounds__(256) void prep_kernel(
    const float* __restrict__ W2, const float* __restrict__ Wo,
    const float* __restrict__ W1,
    float* __restrict__ W2T, float* __restrict__ WoT,
    unsigned short* __restrict__ W1b,
    u64* __restrict__ zbuf, int nwords)
{
    int idx = blockIdx.x * 256 + threadIdx.x;
    if (idx < H1_ * H2_) {
        int h1 = idx / H2_, h2 = idx % H2_;
        W2T[idx] = W2[h2 * H1_ + h1];
    }
    if (idx < H2_ * O_) {
        int h2 = idx / O_, o = idx % O_;
        WoT[idx] = Wo[o * H2_ + h2];
    }
    if (idx < H1_ * I_) {
        W1b[idx] = f2bf(W1[idx]);
    }
    for (int i = idx; i < nwords; i += 256 * 1024)
        zbuf[i] = 0ull;
}

// ---------------------------------------------------------------------------
// Fused K1: bf16 MFMA GEMM + chunk-parallel LIF scan.
// Block = 1024 thr = 16 waves; wave c = time chunk c. 1-D grid 512:
// b = id&63, hg = id>>6 (co-XCD per batch; round-6-verified FETCH drop).
// v2: A-frags load straight from pre-converted Xb (16B load -> MFMA, no cvt
// chain); W1b tile staged once in LDS with 16B-granule XOR swizzle.
// ---------------------------------------------------------------------------
__global__ __launch_bounds__(1024, 1) void fused1_kernel(
    const unsigned short* __restrict__ Xb,  // [B][1024][256] bf16
    const unsigned short* __restrict__ W1b, // [512][256] bf16
    const float* __restrict__ b1,
    const float* __restrict__ tau_m1, const float* __restrict__ tau_n1,
    u64* __restrict__ s1_bits, u64* __restrict__ s1_any)
{
    __shared__ unsigned short w1s[64 * 256];  // 32 KB, swizzled 16B granules
    __shared__ float rbuf[CH_][64][16];       // 64 KB transpose buffers
    __shared__ float vd[CH_][64];
    __shared__ float meS[CH_][64];
    __shared__ float thS[CH_][64];
    __shared__ float memio[64];
    __shared__ int hdirty[64];
    __shared__ int anyd;

    const int tid = threadIdx.x;
    const int h  = tid & 63;
    const int c  = tid >> 6;
    const int id = blockIdx.x;
    const int b  = id & 63;
    const int hg = id >> 6;
    const int n0 = hg * 64;
    const int lr = tid & 15;        // MFMA row/col lane index
    const int lq = (tid >> 4) & 3;  // MFMA k-group / D-row-group

    if (tid < 64) hdirty[tid] = 0;
    if (tid == 0) anyd = 0;

    // ---- stage W1b tile [n0..n0+64)x[0..256) into LDS, swizzled ----
    {
        int row = tid >> 4, c2 = tid & 15;   // row 0..63, c2 = 32B group
        const s8v* gsrc = reinterpret_cast<const s8v*>(
            W1b + (size_t)(n0 + row) * I_ + c2 * 16);
        int sw = row & 7;
        s8v v0 = gsrc[0], v1 = gsrc[1];
        *reinterpret_cast<s8v*>(&w1s[row * 256 + (((c2 * 2) ^ sw) << 3)])     = v0;
        *reinterpret_cast<s8v*>(&w1s[row * 256 + (((c2 * 2 + 1) ^ sw) << 3)]) = v1;
    }
    __syncthreads();

    // ---- GEMM: wave c computes din[t=c*64..][n0..+64] in MFMA frags ----
    // Verified mapping: A row=lr,k=lq*8+j; B col=lr,k=lq*8+j; D col=lr,row=lq*4+r.
    f4v acc[4][4] = {};
    const unsigned short* xb = Xb + ((size_t)b * T_ + c * LL_) * I_;
    const int swb = lr & 7;
    #pragma unroll
    for (int ks = 0; ks < 8; ks++) {
        s8v av[4];
        #pragma unroll
        for (int mi = 0; mi < 4; mi++)
            av[mi] = *reinterpret_cast<const s8v*>(
                xb + (size_t)(mi * 16 + lr) * I_ + ks * 32 + lq * 8);
        s8v bf[4];
        #pragma unroll
        for (int ni = 0; ni < 4; ni++)
            bf[ni] = *reinterpret_cast<const s8v*>(
                &w1s[(ni * 16 + lr) * 256 + ((((ks * 4) + lq) ^ swb) << 3)]);
        #pragma unroll
        for (int mi = 0; mi < 4; mi++)
            #pragma unroll
            for (int ni = 0; ni < 4; ni++)
                acc[mi][ni] = __builtin_amdgcn_mfma_f32_16x16x32_bf16(
                    av[mi], bf[ni], acc[mi][ni], 0, 0, 0);
    }

    // ---- intra-wave transpose: MFMA layout -> scan layout (arr[64]) ----
    const float biasv = b1[n0 + h];
    const int swz_w = (lr & 3) ^ (lr >> 2);
    const int swz_r = (h & 3) ^ ((h >> 2) & 3);
    float arr[LL_];
    #pragma unroll
    for (int mi = 0; mi < 4; mi++) {
        #pragma unroll
        for (int ni = 0; ni < 4; ni++) {
            *reinterpret_cast<float4*>(&rbuf[c][ni * 16 + lr][(lq ^ swz_w) * 4]) =
                make_float4(acc[mi][ni][0], acc[mi][ni][1],
                            acc[mi][ni][2], acc[mi][ni][3]);
        }
        __builtin_amdgcn_wave_barrier();
        #pragma unroll
        for (int jq = 0; jq < 4; jq++) {
            float4 rv = *reinterpret_cast<const float4*>(&rbuf[c][h][(jq ^ swz_r) * 4]);
            arr[mi * 16 + jq * 4 + 0] = rv.x + biasv;
            arr[mi * 16 + jq * 4 + 1] = rv.y + biasv;
            arr[mi * 16 + jq * 4 + 2] = rv.z + biasv;
            arr[mi * 16 + jq * 4 + 3] = rv.w + biasv;
        }
        __builtin_amdgcn_wave_barrier();
    }

    // ---- chunk-parallel exact LIF scan ----
    const int hglob = n0 + h;
    float beta    = 1.f / (1.f + __expf(-tau_n1[hglob]));
    float alpha   = 1.f / (1.f + __expf(-tau_m1[hglob]));
    float ombeta  = 1.f - beta;
    float omalpha = 1.f - alpha;
    float bL = beta;  { bL *= bL; bL *= bL; bL *= bL; bL *= bL; bL *= bL; bL *= bL; }
    float aL = alpha; { aL *= aL; aL *= aL; aL *= aL; aL *= aL; aL *= aL; aL *= aL; }
    float ai = 1.0f / alpha;

    float d1 = 0.f;
    #pragma unroll
    for (int i = 0; i < LL_; i++) {
        d1 = fmaf(beta, d1, ombeta * arr[i]);
        arr[i] = d1;
    }
    vd[c][h] = d1;
    __syncthreads();

    float ds = 0.f;
    for (int cc = 0; cc < c; cc++) ds = fmaf(bL, ds, vd[cc][h]);

    float pc = ds, m = 0.f, api = 1.f, th = 3.4e38f;
    #pragma unroll
    for (int i = 0; i < LL_; i++) {
        pc *= beta;
        float dt = arr[i] + pc;
        arr[i] = dt;
        m = fmaf(alpha, m, omalpha * dt);
        api *= ai;
        th = fminf(th, (1.f - m) * api);
    }
    meS[c][h] = m;
    thS[c][h] = th;
    __syncthreads();

    float v = 0.f; bool dirty = false;
    for (int cc = 0; cc < c; cc++) {
        if (v > thS[cc][h] - GUARD_) dirty = true;
        v = fmaf(aL, v, meS[cc][h]);
    }
    if (v > th - GUARD_) dirty = true;
    if (dirty) { hdirty[h] = 1; atomicOr(&anyd, 1); }
    __syncthreads();

    if (anyd) {
        for (int cc = 0; cc < CH_; cc++) {
            if (c == cc && hdirty[h]) {
                float mi_ = (cc == 0) ? 0.f : memio[h];
                float mo;
                if (mi_ > th - GUARD_) {
                    float mem = mi_;
                    #pragma unroll
                    for (int i = 0; i < LL_; i++) {
                        mem = fmaf(alpha, mem, omalpha * arr[i]);
                        if (mem > 1.f) {
                            atomicOr(&s1_bits[((size_t)b * T_ + cc * LL_ + i) * 8 + hg], 1ull << h);
                            atomicOr(&s1_any[b * 16 + cc], 1ull << i);
                            mem = 0.f;
                        }
                    }
                    mo = mem;
                } else {
                    mo = fmaf(aL, mi_, m);
                }
                memio[h] = mo;
            }
            __syncthreads();
        }
    }
}

// ---------------------------------------------------------------------------
// helper: gather layer-2 input contribution from spiking h1's (rare)
// ---------------------------------------------------------------------------
__device__ __noinline__ float gather_w2(const u64* __restrict__ w,
                                        const float* __restrict__ W2T, int hglob)
{
    float acc = 0.f;
    for (int q = 0; q < 8; q++) {
        u64 mq = w[q];
        while (mq) {
            int h1 = __ffsll((long long)mq) - 1;
            mq &= mq - 1;
            acc += W2T[(size_t)(q * 64 + h1) * H2_ + hglob];
        }
    }
    return acc;
}

// ---------------------------------------------------------------------------
// K3: layer-2 chunk-parallel exact LIF scan (input = b2 + sparse spikes).
// ---------------------------------------------------------------------------
__global__ __launch_bounds__(1024) void scan2_kernel(
    const float* __restrict__ W2T, const float* __restrict__ b2,
    const float* __restrict__ tau_m2, const float* __restrict__ tau_n2,
    const u64* __restrict__ s1_bits, const u64* __restrict__ s1_any,
    u64* __restrict__ s2_bits, u64* __restrict__ s2_any)
{
    __shared__ float vd[CH_][64];
    __shared__ float meS[CH_][64];
    __shared__ float thS[CH_][64];
    __shared__ float memio[64];
    __shared__ int hdirty[64];
    __shared__ int anyd;

    int tid = threadIdx.x;
    int h = tid & 63, c = tid >> 6;
    int id = blockIdx.x;
    int b  = id & 63;
    int hg = id >> 6;
    int hglob = hg * 64 + h;

    if (tid < 64) hdirty[tid] = 0;
    if (tid == 0) anyd = 0;

    float beta    = 1.f / (1.f + __expf(-tau_n2[hglob]));
    float alpha   = 1.f / (1.f + __expf(-tau_m2[hglob]));
    float ombeta  = 1.f - beta;
    float omalpha = 1.f - alpha;
    float bias    = b2[hglob];
    float bL = beta;  { bL *= bL; bL *= bL; bL *= bL; bL *= bL; bL *= bL; bL *= bL; }
    float aL = alpha; { aL *= aL; aL *= aL; aL *= aL; aL *= aL; aL *= aL; aL *= aL; }
    float ai = 1.0f / alpha;

    float arr[LL_];
    u64 aw = s1_any[b * 16 + c];
    float d2 = 0.f;
    if (aw == 0) {
        #pragma unroll
        for (int i = 0; i < LL_; i++) {
            d2 = fmaf(beta, d2, ombeta * bias);
            arr[i] = d2;
        }
    } else {
        #pragma unroll
        for (int i = 0; i < LL_; i++) {
            float dv = bias;
            if ((aw >> i) & 1ull)
                dv += gather_w2(s1_bits + ((size_t)b * T_ + c * LL_ + i) * 8, W2T, hglob);
            d2 = fmaf(beta, d2, ombeta * dv);
            arr[i] = d2;
        }
    }
    vd[c][h] = d2;
    __syncthreads();

    float ds = 0.f;
    for (int cc = 0; cc < c; cc++) ds = fmaf(bL, ds, vd[cc][h]);

    float pc = ds, m = 0.f, api = 1.f, th = 3.4e38f;
    #pragma unroll
    for (int i = 0; i < LL_; i++) {
        pc *= beta;
        float dt = arr[i] + pc;
        arr[i] = dt;
        m = fmaf(alpha, m, omalpha * dt);
        api *= ai;
        th = fminf(th, (1.f - m) * api);
    }
    meS[c][h] = m;
    thS[c][h] = th;
    __syncthreads();

    float v = 0.f; bool dirty = false;
    for (int cc = 0; cc < c; cc++) {
        if (v > thS[cc][h] - GUARD_) dirty = true;
        v = fmaf(aL, v, meS[cc][h]);
    }
    if (v > th - GUARD_) dirty = true;
    if (dirty) { hdirty[h] = 1; atomicOr(&anyd, 1); }
    __syncthreads();

    if (anyd) {
        for (int cc = 0; cc < CH_; cc++) {
            if (c == cc && hdirty[h]) {
                float mi_ = (cc == 0) ? 0.f : memio[h];
                float mo;
                if (mi_ > th - GUARD_) {
                    float mem = mi_;
                    #pragma unroll
                    for (int i = 0; i < LL_; i++) {
                        mem = fmaf(alpha, mem, omalpha * arr[i]);
                        if (mem > 1.f) {
                            atomicOr(&s2_bits[((size_t)b * T_ + cc * LL_ + i) * 8 + hg], 1ull << h);
                            atomicOr(&s2_any[b * 16 + cc], 1ull << i);
                            mem = 0.f;
                        }
                    }
                    mo = mem;
                } else {
                    mo = fmaf(aL, mi_, m);
                }
                memio[h] = mo;
            }
            __syncthreads();
        }
    }
}

// ---------------------------------------------------------------------------
// K4: output = sigmoid(bo + sum over spiking h2 of WoT[h2][:]), float4 stores
// ---------------------------------------------------------------------------
__global__ __launch_bounds__(256) void out_kernel(
    const float* __restrict__ WoT, const float* __restrict__ bo,
    const u64* __restrict__ s2_bits, const u64* __restrict__ s2_any,
    float* __restrict__ out)
{
    int idx = blockIdx.x * 256 + threadIdx.x;
    int o4 = idx & 31;
    int t  = (idx >> 5) & 1023;
    int b  = idx >> 15;

    float4 z = *reinterpret_cast<const float4*>(bo + o4 * 4);
    if ((s2_any[b * 16 + (t >> 6)] >> (t & 63)) & 1ull) {
        const u64* w = s2_bits + ((size_t)b * T_ + t) * 8;
        for (int q = 0; q < 8; q++) {
            u64 mq = w[q];
            while (mq) {
                int h2 = __ffsll((long long)mq) - 1;
                mq &= mq - 1;
                float4 wv = *reinterpret_cast<const float4*>(
                    WoT + (size_t)(q * 64 + h2) * O_ + o4 * 4);
                z.x += wv.x; z.y += wv.y; z.z += wv.z; z.w += wv.w;
            }
        }
    }
    float4 r;
    r.x = 1.f / (1.f + __expf(-z.x));
    r.y = 1.f / (1.f + __expf(-z.y));
    r.z = 1.f / (1.f + __expf(-z.z));
    r.w = 1.f / (1.f + __expf(-z.w));
    *reinterpret_cast<float4*>(out + ((size_t)b * T_ + t) * O_ + o4 * 4) = r;
}

// ---------------------------------------------------------------------------
// Launch
// ---------------------------------------------------------------------------
extern "C" void kernel_launch(void* const* d_in, const int* in_sizes, int n_in,
                              void* d_out, int out_size, void* d_ws, size_t ws_size,
                              hipStream_t stream)
{
    const float* x      = (const float*)d_in[0];
    const float* W1     = (const float*)d_in[1];
    const float* b1     = (const float*)d_in[2];
    const float* tau_m1 = (const float*)d_in[3];
    const float* tau_n1 = (const float*)d_in[4];
    const float* W2     = (const float*)d_in[5];
    const float* b2     = (const float*)d_in[6];
    const float* tau_m2 = (const float*)d_in[7];
    const float* tau_n2 = (const float*)d_in[8];
    const float* Wo     = (const float*)d_in[9];
    const float* bo     = (const float*)d_in[10];
    float* out = (float*)d_out;

    char* ws = (char*)d_ws;
    size_t off = 0;
    float* W2T = (float*)(ws + off);            off += (size_t)H1_ * H2_ * 4;   // 1 MB
    float* WoT = (float*)(ws + off);            off += (size_t)H2_ * O_ * 4;    // 256 KB
    unsigned short* W1b = (unsigned short*)(ws + off); off += (size_t)H1_ * I_ * 2; // 256 KB
    unsigned short* Xb  = (unsigned short*)(ws + off); off += (size_t)B_ * T_ * I_ * 2; // 32 MB
    size_t zero_begin = off;
    u64* s1_any  = (u64*)(ws + off); off += (size_t)B_ * 16 * 8;
    u64* s2_any  = (u64*)(ws + off); off += (size_t)B_ * 16 * 8;
    u64* s1_bits = (u64*)(ws + off); off += (size_t)B_ * T_ * 8 * 8;            // 4 MB
    u64* s2_bits = (u64*)(ws + off); off += (size_t)B_ * T_ * 8 * 8;            // 4 MB
    int zero_words = (int)((off - zero_begin) / 8);

    xcvt_kernel<<<dim3((B_ * T_ * I_) / (256 * 8)), dim3(256), 0, stream>>>(x, Xb);

    prep_kernel<<<dim3(1024), dim3(256), 0, stream>>>(
        W2, Wo, W1, W2T, WoT, W1b, (u64*)(ws + zero_begin), zero_words);

    fused1_kernel<<<dim3(512), dim3(1024), 0, stream>>>(
        Xb, W1b, b1, tau_m1, tau_n1, s1_bits, s1_any);

    scan2_kernel<<<dim3(512), dim3(1024), 0, stream>>>(
        W2T, b2, tau_m2, tau_n2, s1_bits, s1_any, s2_bits, s2_any);

    out_kernel<<<dim3(B_ * 128), dim3(256), 0, stream>>>(
        WoT, bo, s2_bits, s2_any, out);
}